// Round 10
// baseline (223.413 us; speedup 1.0000x reference)
//
#include <hip/hip_runtime.h>
#include <hip/hip_bf16.h>

typedef __attribute__((ext_vector_type(8))) short short8;
typedef __attribute__((ext_vector_type(4))) float f32x4;
typedef __attribute__((ext_vector_type(4))) unsigned uint4v;
typedef __attribute__((ext_vector_type(2))) unsigned uint2v;

#define NCELL 8192
#define NGENE 10000
#define KD 32
#define ZD 100
#define HD 256
#define GD 100    // z_dim of output (gen_Z rows)
#define NGB 625   // gene units of 16 (625*16 == 10000 exactly)
#define NGPAD 10016
#define QSL 16    // cell slices of 512

__device__ __forceinline__ float gelu_exact(float x) {
    return 0.5f * x * (1.0f + erff(x * 0.70710678118654752f));
}
__device__ __forceinline__ ushort bf16bits(float x) {
    __hip_bfloat16 h = __float2bfloat16(x);
    return *reinterpret_cast<ushort*>(&h);
}
__device__ __forceinline__ f32x4 ntload4(const float* p) {
    return __builtin_nontemporal_load(reinterpret_cast<const f32x4*>(p));
}
__device__ __forceinline__ short8 ld8(const ushort* p) {
    return *reinterpret_cast<const short8*>(p);
}

// ---------------- Kernel 1: keys -> bf16 hi/lo A-fragments for S^T (slot perm cmap, validated R7)
__global__ void key_kernel(const float* __restrict__ rawZ,
                           const float* __restrict__ Wz1, const float* __restrict__ bz1,
                           const float* __restrict__ Wz2, const float* __restrict__ bz2,
                           ushort* __restrict__ khiA, ushort* __restrict__ kloA,
                           unsigned* __restrict__ kmax2u) {
    __shared__ float z[8][ZD];
    __shared__ float h[8][HD];
    const int t = threadIdx.x;
    const int c0 = blockIdx.x * 8;
    for (int idx = t; idx < 8 * ZD; idx += 256) {
        int cell = idx / ZD, i = idx - cell * ZD;
        z[cell][i] = rawZ[i * NCELL + c0 + cell];
    }
    __syncthreads();
    float a[8];
#pragma unroll
    for (int cl = 0; cl < 8; ++cl) a[cl] = bz1[t];
    for (int i = 0; i < ZD; ++i) {
        float wv = Wz1[i * HD + t];
#pragma unroll
        for (int cl = 0; cl < 8; ++cl) a[cl] += z[cl][i] * wv;
    }
#pragma unroll
    for (int cl = 0; cl < 8; ++cl) h[cl][t] = gelu_exact(a[cl]);
    __syncthreads();
    const int cell = t >> 5, kk = t & 31;
    float b = bz2[kk];
    for (int j = 0; j < HD; ++j) b += h[cell][j] * Wz2[j * KD + kk];
    const int c = c0 + cell;
    const int c16 = c & 15;
    const int G = c16 >> 2;
    const int s = (c16 & 3) | ((((G & 1) << 1) | (G >> 1)) << 2);  // slot = (c&3) | cmap(G)<<2
    __hip_bfloat16 hi = __float2bfloat16(b);
    float hif = __bfloat162float(hi);
    int idx = ((c >> 4) * 64 + s + 16 * (kk >> 3)) * 8 + (kk & 7);
    khiA[idx] = *reinterpret_cast<ushort*>(&hi);
    kloA[idx] = bf16bits(b - hif);
    float sq = b * b;
#pragma unroll
    for (int off = 16; off > 0; off >>= 1) sq += __shfl_xor(sq, off, 32);
    if (kk == 0) atomicMax(kmax2u, __float_as_uint(sq));
}

// ---------------- Kernel 2: q -> bf16 hi/lo B-fragments (padded to 10016 genes), Mg bound
__global__ void query_kernel(const float* __restrict__ Grep,
                             const float* __restrict__ Wg1, const float* __restrict__ bg1,
                             const float* __restrict__ Wg2, const float* __restrict__ bg2,
                             const unsigned* __restrict__ kmax2u,
                             ushort* __restrict__ qBhi, ushort* __restrict__ qBlo,
                             float* __restrict__ Mg) {
    __shared__ float gr[8][GD];
    __shared__ float hq[8][KD];
    const int t = threadIdx.x;
    const int g0 = blockIdx.x * 8;
    for (int idx = t; idx < 8 * GD; idx += 256) {
        int ge = idx / GD, i = idx - ge * GD;
        int g = g0 + ge;
        gr[ge][i] = (g < NGENE) ? Grep[(size_t)g * GD + i] : 0.0f;
    }
    __syncthreads();
    const int ge = t >> 5, kk = t & 31;
    float a = bg1[kk];
    for (int i = 0; i < GD; ++i) a += gr[ge][i] * Wg1[i * KD + kk];
    hq[ge][kk] = gelu_exact(a);
    __syncthreads();
    float b = bg2[kk];
#pragma unroll
    for (int j = 0; j < KD; ++j) b += hq[ge][j] * Wg2[j * KD + kk];
    float qv = b * 0.17677669529663687f; // fold 1/sqrt(d_k)
    const int g = g0 + ge;
    __hip_bfloat16 hi = __float2bfloat16(qv);
    float hif = __bfloat162float(hi);
    int idx = ((g >> 4) * 64 + (g & 15) + 16 * (kk >> 3)) * 8 + (kk & 7);
    qBhi[idx] = *reinterpret_cast<ushort*>(&hi);
    qBlo[idx] = bf16bits(qv - hif);
    float sq = qv * qv;
#pragma unroll
    for (int off = 16; off > 0; off >>= 1) sq += __shfl_xor(sq, off, 32);
    if (kk == 0) {
        float km2 = __uint_as_float(*kmax2u);
        Mg[g] = sqrtf(sq * km2) + 25.0f;   // static softmax shift; exp(l-M) <= 1 always
    }
}

// ---------------- Kernel 3: genZB — gen_Z bf16, PV B-frag, tau k-order, DB-MAJOR layout
__global__ void vprep_kernel(const float* __restrict__ genZ, ushort* __restrict__ genZB) {
    int o = blockIdx.x * 256 + threadIdx.x; // 917,504 total
    int j = o & 7;
    int tj = (j & 1) | ((j & 2) << 1) | ((j & 4) >> 1);   // tau
    int l = (o >> 3) & 63;
    int cb = (o >> 9) & 255;
    int db = o >> 17;
    int c = cb * 32 + ((l >> 4) & 3) * 8 + tj;
    int d = db * 16 + (l & 15);
    float v = (d < GD) ? genZ[(size_t)d * NCELL + c] : 0.0f;
    genZB[o] = bf16bits(v);
}

// ---------------- Kernel 4: fused partial — V in 112KB LDS (R9) + gumbel prefetch DISTANCE 3
// (4 named register sets, 4-step unrolled body; K at distance 1). Targets exposed HBM latency.
#define STEP_COMPUTE(kh0_, kh1_, kl0_, kl1_, u0_, u1_)                                      \
    do {                                                                                    \
        short8 v0 = ld8(vp);         short8 v1 = ld8(vp + 8192);                            \
        short8 v2 = ld8(vp + 16384); short8 v3 = ld8(vp + 24576);                           \
        short8 v4 = ld8(vp + 32768); short8 v5 = ld8(vp + 40960);                           \
        short8 v6 = ld8(vp + 49152); vp += 512;                                             \
        __builtin_amdgcn_s_setprio(1);                                                      \
        f32x4 s0 = __builtin_amdgcn_mfma_f32_16x16x32_bf16(kh0_, qh, z4, 0, 0, 0);          \
        s0 = __builtin_amdgcn_mfma_f32_16x16x32_bf16(kl0_, qh, s0, 0, 0, 0);                \
        s0 = __builtin_amdgcn_mfma_f32_16x16x32_bf16(kh0_, ql, s0, 0, 0, 0);                \
        f32x4 s1 = __builtin_amdgcn_mfma_f32_16x16x32_bf16(kh1_, qh, z4, 0, 0, 0);          \
        s1 = __builtin_amdgcn_mfma_f32_16x16x32_bf16(kl1_, qh, s1, 0, 0, 0);                \
        s1 = __builtin_amdgcn_mfma_f32_16x16x32_bf16(kh1_, ql, s1, 0, 0, 0);                \
        float p0 = __expf(s0.x + u0_.x + negM);                                             \
        float p1 = __expf(s0.y + u0_.y + negM);                                             \
        float p2 = __expf(s0.z + u0_.z + negM);                                             \
        float p3 = __expf(s0.w + u0_.w + negM);                                             \
        float p4 = __expf(s1.x + u1_.x + negM);                                             \
        float p5 = __expf(s1.y + u1_.y + negM);                                             \
        float p6 = __expf(s1.z + u1_.z + negM);                                             \
        float p7 = __expf(s1.w + u1_.w + negM);                                             \
        L += ((p0 + p1) + (p2 + p3)) + ((p4 + p5) + (p6 + p7));                             \
        unsigned w00, w01, w10, w11;                                                        \
        asm("v_cvt_pk_bf16_f32 %0, %1, %2" : "=v"(w00) : "v"(p0), "v"(p1));                 \
        asm("v_cvt_pk_bf16_f32 %0, %1, %2" : "=v"(w01) : "v"(p2), "v"(p3));                 \
        asm("v_cvt_pk_bf16_f32 %0, %1, %2" : "=v"(w10) : "v"(p4), "v"(p5));                 \
        asm("v_cvt_pk_bf16_f32 %0, %1, %2" : "=v"(w11) : "v"(p6), "v"(p7));                 \
        uint2v rA = __builtin_amdgcn_permlane32_swap(w00, w10, false, false);               \
        uint2v rB = __builtin_amdgcn_permlane32_swap(w01, w11, false, false);               \
        uint4v pau = {rA.x, rA.y, rB.x, rB.y};                                              \
        short8 pa = *reinterpret_cast<short8*>(&pau);                                       \
        acc[0] = __builtin_amdgcn_mfma_f32_16x16x32_bf16(pa, v0, acc[0], 0, 0, 0);          \
        acc[1] = __builtin_amdgcn_mfma_f32_16x16x32_bf16(pa, v1, acc[1], 0, 0, 0);          \
        acc[2] = __builtin_amdgcn_mfma_f32_16x16x32_bf16(pa, v2, acc[2], 0, 0, 0);          \
        acc[3] = __builtin_amdgcn_mfma_f32_16x16x32_bf16(pa, v3, acc[3], 0, 0, 0);          \
        acc[4] = __builtin_amdgcn_mfma_f32_16x16x32_bf16(pa, v4, acc[4], 0, 0, 0);          \
        acc[5] = __builtin_amdgcn_mfma_f32_16x16x32_bf16(pa, v5, acc[5], 0, 0, 0);          \
        acc[6] = __builtin_amdgcn_mfma_f32_16x16x32_bf16(pa, v6, acc[6], 0, 0, 0);          \
        __builtin_amdgcn_s_setprio(0);                                                      \
    } while (0)

#define LK_A(s_) { khA0 = ld8(kb + (s_) * 1024);  khA1 = ld8(kb + (s_) * 1024 + 512);       \
                   klA0 = ld8(klb + (s_) * 1024); klA1 = ld8(klb + (s_) * 1024 + 512); }
#define LK_B(s_) { khB0 = ld8(kb + (s_) * 1024);  khB1 = ld8(kb + (s_) * 1024 + 512);       \
                   klB0 = ld8(klb + (s_) * 1024); klB1 = ld8(klb + (s_) * 1024 + 512); }
#define LG(i, s_) { int sc_ = (s_) < 15 ? (s_) : 15;                                        \
                    g##i##a = ntload4(gp0 + sc_ * 32); g##i##b = ntload4(gp0 + sc_ * 32 + 16); }

__launch_bounds__(512)
__global__ void fused_kernel(const float* __restrict__ gumbel,
                             const ushort* __restrict__ khiA, const ushort* __restrict__ kloA,
                             const ushort* __restrict__ qBhi, const ushort* __restrict__ qBlo,
                             const float* __restrict__ Mg,
                             const ushort* __restrict__ genZB,
                             float* __restrict__ part, float* __restrict__ Lpart) {
    __shared__ __align__(16) ushort vlds[7 * 8192];   // 112 KB: V slice, db-major
    const int t = threadIdx.x, lane = t & 63, w = t >> 6;
    const int b = blockIdx.x;
    const int q = b & 15;          // slice; slices s and s+8 share an XCD (K slice L2-hot)
    const int ib = b >> 4;         // 16 blocks per slice
    // ---- stage V slice (7 contiguous 16KB pieces, linear copy)
    {
        f32x4* vdst = reinterpret_cast<f32x4*>(vlds);
        const f32x4* vsrc = reinterpret_cast<const f32x4*>(genZB);
        for (int i = t; i < 7168; i += 512) {
            int db = i >> 10, rem = i & 1023;
            vdst[i] = vsrc[db * 16384 + q * 1024 + rem];
        }
    }
    __syncthreads();   // the only barrier

    const int gx = lane & 15, bq = lane >> 4;
    const int cmap4 = (((bq & 1) << 1) | (bq >> 1)) << 2;   // {0,8,4,12}
    const ushort* kb  = khiA + q * 16384 + lane * 8;
    const ushort* klb = kloA + q * 16384 + lane * 8;
    const f32x4 z4 = {0.f, 0.f, 0.f, 0.f};

    for (int u = ib * 8 + w; u < NGB; u += 128) {
        const float negM = -Mg[u * 16 + gx];
        short8 qh = ld8(qBhi + (size_t)u * 512 + lane * 8);
        short8 ql = ld8(qBlo + (size_t)u * 512 + lane * 8);
        const float* gp0 = gumbel + (size_t)(u * 16 + gx) * NCELL + q * 512 + cmap4;
        const ushort* vp = vlds + lane * 8;
        f32x4 acc[7];
#pragma unroll
        for (int i = 0; i < 7; ++i) acc[i] = z4;
        float L = 0.f;
        // named pipeline registers
        short8 khA0, khA1, klA0, klA1, khB0, khB1, klB0, klB1;
        f32x4 g0a, g0b, g1a, g1b, g2a, g2b, g3a, g3b;
        // prologue: gumbel steps 0..2 in flight (distance 3), K step 0
        LG(0, 0); LG(1, 1); LG(2, 2);
        LK_A(0);
        for (int it = 0; it < 4; ++it) {   // steps 4it .. 4it+3
            const int s = 4 * it;
            LK_B(s + 1);
            LG(3, s + 3);
            STEP_COMPUTE(khA0, khA1, klA0, klA1, g0a, g0b);      // step s
            LK_A(s + 2);
            LG(0, s + 4);
            STEP_COMPUTE(khB0, khB1, klB0, klB1, g1a, g1b);      // step s+1
            LK_B(s + 3);
            LG(1, s + 5);
            STEP_COMPUTE(khA0, khA1, klA0, klA1, g2a, g2b);      // step s+2
            { int sc = (s + 4) < 15 ? (s + 4) : 15; LK_A(sc); }
            LG(2, s + 6);
            STEP_COMPUTE(khB0, khB1, klB0, klB1, g3a, g3b);      // step s+3
        }
        // L: lanes sharing gx hold disjoint-cell partials of the same gene
        L += __shfl_xor(L, 16, 64);
        L += __shfl_xor(L, 32, 64);
        const int wv = q * NGB + u;
        if (lane < 16)
            __builtin_nontemporal_store(L, Lpart + (size_t)wv * 16 + lane);
        float* pp = part + (size_t)wv * 7 * 256;
#pragma unroll
        for (int tile = 0; tile < 7; ++tile)
            __builtin_nontemporal_store(acc[tile],
                reinterpret_cast<f32x4*>(pp + tile * 256 + lane * 4));
    }
}

// ---------------- Kernel 5: combine 16 slice-partials + normalize
__global__ void combine_kernel(const float* __restrict__ part, const float* __restrict__ Lpart,
                               float* __restrict__ out) {
    const int gb = blockIdx.x;   // 625
    const int t = threadIdx.x;   // 512
    __shared__ float Linv[16];
    if (t < 16) {
        float s = 0.f;
        for (int qq = 0; qq < QSL; ++qq) s += Lpart[(size_t)(qq * NGB + gb) * 16 + t];
        Linv[t] = 1.0f / s;
    }
    __syncthreads();
    if (t < 448) {
        const int tile = t >> 6, lane = t & 63;
        const int d = tile * 16 + (lane & 15);
        f32x4 ssum = {0.f, 0.f, 0.f, 0.f};
        for (int qq = 0; qq < QSL; ++qq)
            ssum += *reinterpret_cast<const f32x4*>(
                part + ((size_t)(qq * NGB + gb) * 7 + tile) * 256 + lane * 4);
        if (d < GD) {
            const int gl0 = 4 * (lane >> 4);   // C/D: col=lane&15 (d), row=4*(lane>>4)+r (gene)
            f32x4 li = {Linv[gl0], Linv[gl0 + 1], Linv[gl0 + 2], Linv[gl0 + 3]};
            f32x4 o = ssum * li;
            *reinterpret_cast<f32x4*>(out + (size_t)d * NGENE + gb * 16 + gl0) = o;
        }
    }
}

extern "C" void kernel_launch(void* const* d_in, const int* in_sizes, int n_in,
                              void* d_out, int out_size, void* d_ws, size_t ws_size,
                              hipStream_t stream) {
    const float* rawZ  = (const float*)d_in[0];
    const float* genZ  = (const float*)d_in[1];
    const float* Grep  = (const float*)d_in[2];
    const float* gumb  = (const float*)d_in[3];
    const float* Wz1   = (const float*)d_in[4];
    const float* bz1   = (const float*)d_in[5];
    const float* Wz2   = (const float*)d_in[6];
    const float* bz2   = (const float*)d_in[7];
    const float* Wg1   = (const float*)d_in[8];
    const float* bg1   = (const float*)d_in[9];
    const float* Wg2   = (const float*)d_in[10];
    const float* bg2   = (const float*)d_in[11];
    float* out = (float*)d_out;

    char* ws = (char*)d_ws;
    ushort*   khiA  = (ushort*)ws;                           // 512K
    ushort*   kloA  = (ushort*)(ws + 524288);                // 512K
    ushort*   qBhi  = (ushort*)(ws + 1048576);               // 640K (10016 genes)
    ushort*   qBlo  = (ushort*)(ws + 1703936);               // 640K
    ushort*   genZB = (ushort*)(ws + 2359296);               // 1.75M (7 db, db-major)
    float*    MgA   = (float*)(ws + 4456448);                // 40K
    unsigned* kmax  = (unsigned*)(ws + 4497408);             // 256B
    const size_t base_off = 4497664;

    float* partA  = (float*)(ws + base_off);                 // 16*625*7*256*4 = 71.7 MB
    float* LpartA = partA + (size_t)QSL * NGB * 7 * 256;     // 640 KB

    hipMemsetAsync(kmax, 0, 4, stream);
    hipLaunchKernelGGL(key_kernel,   dim3(NCELL / 8), dim3(256), 0, stream,
                       rawZ, Wz1, bz1, Wz2, bz2, khiA, kloA, kmax);
    hipLaunchKernelGGL(query_kernel, dim3(NGPAD / 8), dim3(256), 0, stream,
                       Grep, Wg1, bg1, Wg2, bg2, kmax, qBhi, qBlo, MgA);
    hipLaunchKernelGGL(vprep_kernel, dim3(917504 / 256), dim3(256), 0, stream,
                       genZ, genZB);
    hipLaunchKernelGGL(fused_kernel, dim3(256), dim3(512), 0, stream,
                       gumb, khiA, kloA, qBhi, qBlo, MgA, genZB, partA, LpartA);
    hipLaunchKernelGGL(combine_kernel, dim3(NGB), dim3(512), 0, stream,
                       partA, LpartA, out);
}

// Round 11
// 195.572 us; speedup vs baseline: 1.1424x; 1.1424x over previous
//
#include <hip/hip_runtime.h>
#include <hip/hip_bf16.h>

typedef __attribute__((ext_vector_type(8))) short short8;
typedef __attribute__((ext_vector_type(4))) float f32x4;
typedef __attribute__((ext_vector_type(4))) unsigned uint4v;
typedef __attribute__((ext_vector_type(2))) unsigned uint2v;

#define NCELL 8192
#define NGENE 10000
#define KD 32
#define ZD 100
#define HD 256
#define GD 100    // z_dim of output (gen_Z rows)
#define NGB 625   // gene units of 16 (625*16 == 10000 exactly)
#define NGPAD 10016
#define QSL 16    // cell slices of 512

__device__ __forceinline__ float gelu_exact(float x) {
    return 0.5f * x * (1.0f + erff(x * 0.70710678118654752f));
}
__device__ __forceinline__ ushort bf16bits(float x) {
    __hip_bfloat16 h = __float2bfloat16(x);
    return *reinterpret_cast<ushort*>(&h);
}
__device__ __forceinline__ f32x4 ld4(const float* p) {
    return *reinterpret_cast<const f32x4*>(p);
}
__device__ __forceinline__ short8 ld8(const ushort* p) {
    return *reinterpret_cast<const short8*>(p);
}

// ---------------- Kernel 1: keys -> bf16 hi/lo A-fragments for S^T (slot perm cmap, validated R7)
__global__ void key_kernel(const float* __restrict__ rawZ,
                           const float* __restrict__ Wz1, const float* __restrict__ bz1,
                           const float* __restrict__ Wz2, const float* __restrict__ bz2,
                           ushort* __restrict__ khiA, ushort* __restrict__ kloA,
                           unsigned* __restrict__ kmax2u) {
    __shared__ float z[8][ZD];
    __shared__ float h[8][HD];
    const int t = threadIdx.x;
    const int c0 = blockIdx.x * 8;
    for (int idx = t; idx < 8 * ZD; idx += 256) {
        int cell = idx / ZD, i = idx - cell * ZD;
        z[cell][i] = rawZ[i * NCELL + c0 + cell];
    }
    __syncthreads();
    float a[8];
#pragma unroll
    for (int cl = 0; cl < 8; ++cl) a[cl] = bz1[t];
    for (int i = 0; i < ZD; ++i) {
        float wv = Wz1[i * HD + t];
#pragma unroll
        for (int cl = 0; cl < 8; ++cl) a[cl] += z[cl][i] * wv;
    }
#pragma unroll
    for (int cl = 0; cl < 8; ++cl) h[cl][t] = gelu_exact(a[cl]);
    __syncthreads();
    const int cell = t >> 5, kk = t & 31;
    float b = bz2[kk];
    for (int j = 0; j < HD; ++j) b += h[cell][j] * Wz2[j * KD + kk];
    const int c = c0 + cell;
    const int c16 = c & 15;
    const int G = c16 >> 2;
    const int s = (c16 & 3) | ((((G & 1) << 1) | (G >> 1)) << 2);  // slot = (c&3) | cmap(G)<<2
    __hip_bfloat16 hi = __float2bfloat16(b);
    float hif = __bfloat162float(hi);
    int idx = ((c >> 4) * 64 + s + 16 * (kk >> 3)) * 8 + (kk & 7);
    khiA[idx] = *reinterpret_cast<ushort*>(&hi);
    kloA[idx] = bf16bits(b - hif);
    float sq = b * b;
#pragma unroll
    for (int off = 16; off > 0; off >>= 1) sq += __shfl_xor(sq, off, 32);
    if (kk == 0) atomicMax(kmax2u, __float_as_uint(sq));
}

// ---------------- Kernel 2: q -> bf16 hi/lo B-fragments (padded to 10016 genes), Mg bound
__global__ void query_kernel(const float* __restrict__ Grep,
                             const float* __restrict__ Wg1, const float* __restrict__ bg1,
                             const float* __restrict__ Wg2, const float* __restrict__ bg2,
                             const unsigned* __restrict__ kmax2u,
                             ushort* __restrict__ qBhi, ushort* __restrict__ qBlo,
                             float* __restrict__ Mg) {
    __shared__ float gr[8][GD];
    __shared__ float hq[8][KD];
    const int t = threadIdx.x;
    const int g0 = blockIdx.x * 8;
    for (int idx = t; idx < 8 * GD; idx += 256) {
        int ge = idx / GD, i = idx - ge * GD;
        int g = g0 + ge;
        gr[ge][i] = (g < NGENE) ? Grep[(size_t)g * GD + i] : 0.0f;
    }
    __syncthreads();
    const int ge = t >> 5, kk = t & 31;
    float a = bg1[kk];
    for (int i = 0; i < GD; ++i) a += gr[ge][i] * Wg1[i * KD + kk];
    hq[ge][kk] = gelu_exact(a);
    __syncthreads();
    float b = bg2[kk];
#pragma unroll
    for (int j = 0; j < KD; ++j) b += hq[ge][j] * Wg2[j * KD + kk];
    float qv = b * 0.17677669529663687f; // fold 1/sqrt(d_k)
    const int g = g0 + ge;
    __hip_bfloat16 hi = __float2bfloat16(qv);
    float hif = __bfloat162float(hi);
    int idx = ((g >> 4) * 64 + (g & 15) + 16 * (kk >> 3)) * 8 + (kk & 7);
    qBhi[idx] = *reinterpret_cast<ushort*>(&hi);
    qBlo[idx] = bf16bits(qv - hif);
    float sq = qv * qv;
#pragma unroll
    for (int off = 16; off > 0; off >>= 1) sq += __shfl_xor(sq, off, 32);
    if (kk == 0) {
        float km2 = __uint_as_float(*kmax2u);
        Mg[g] = sqrtf(sq * km2) + 25.0f;   // static softmax shift; exp(l-M) <= 1 always
    }
}

// ---------------- Kernel 3: genZB — gen_Z bf16, PV B-frag, tau k-order, DB-MAJOR layout
__global__ void vprep_kernel(const float* __restrict__ genZ, ushort* __restrict__ genZB) {
    int o = blockIdx.x * 256 + threadIdx.x; // 917,504 total
    int j = o & 7;
    int tj = (j & 1) | ((j & 2) << 1) | ((j & 4) >> 1);   // tau
    int l = (o >> 3) & 63;
    int cb = (o >> 9) & 255;
    int db = o >> 17;
    int c = cb * 32 + ((l >> 4) & 3) * 8 + tj;
    int d = db * 16 + (l & 15);
    float v = (d < GD) ? genZ[(size_t)d * NCELL + c] : 0.0f;
    genZB[o] = bf16bits(v);
}

// ---------------- Kernel 4: fused partial — V staged ONCE in 112KB LDS, barrier-free
// gene-unit loop, K+gumbel register double-buffered (distance 1). R9 structure;
// NT hints REMOVED (L3 retention on gumbel + L3-resident partials), setprio REMOVED.
#define STEP_COMPUTE(kh0_, kh1_, kl0_, kl1_, u0_, u1_)                                      \
    do {                                                                                    \
        short8 v0 = ld8(vp);         short8 v1 = ld8(vp + 8192);                            \
        short8 v2 = ld8(vp + 16384); short8 v3 = ld8(vp + 24576);                           \
        short8 v4 = ld8(vp + 32768); short8 v5 = ld8(vp + 40960);                           \
        short8 v6 = ld8(vp + 49152); vp += 512;                                             \
        f32x4 s0 = __builtin_amdgcn_mfma_f32_16x16x32_bf16(kh0_, qh, z4, 0, 0, 0);          \
        s0 = __builtin_amdgcn_mfma_f32_16x16x32_bf16(kl0_, qh, s0, 0, 0, 0);                \
        s0 = __builtin_amdgcn_mfma_f32_16x16x32_bf16(kh0_, ql, s0, 0, 0, 0);                \
        f32x4 s1 = __builtin_amdgcn_mfma_f32_16x16x32_bf16(kh1_, qh, z4, 0, 0, 0);          \
        s1 = __builtin_amdgcn_mfma_f32_16x16x32_bf16(kl1_, qh, s1, 0, 0, 0);                \
        s1 = __builtin_amdgcn_mfma_f32_16x16x32_bf16(kh1_, ql, s1, 0, 0, 0);                \
        float p0 = __expf(s0.x + u0_.x + negM);                                             \
        float p1 = __expf(s0.y + u0_.y + negM);                                             \
        float p2 = __expf(s0.z + u0_.z + negM);                                             \
        float p3 = __expf(s0.w + u0_.w + negM);                                             \
        float p4 = __expf(s1.x + u1_.x + negM);                                             \
        float p5 = __expf(s1.y + u1_.y + negM);                                             \
        float p6 = __expf(s1.z + u1_.z + negM);                                             \
        float p7 = __expf(s1.w + u1_.w + negM);                                             \
        L += ((p0 + p1) + (p2 + p3)) + ((p4 + p5) + (p6 + p7));                             \
        unsigned w00, w01, w10, w11;                                                        \
        asm("v_cvt_pk_bf16_f32 %0, %1, %2" : "=v"(w00) : "v"(p0), "v"(p1));                 \
        asm("v_cvt_pk_bf16_f32 %0, %1, %2" : "=v"(w01) : "v"(p2), "v"(p3));                 \
        asm("v_cvt_pk_bf16_f32 %0, %1, %2" : "=v"(w10) : "v"(p4), "v"(p5));                 \
        asm("v_cvt_pk_bf16_f32 %0, %1, %2" : "=v"(w11) : "v"(p6), "v"(p7));                 \
        uint2v rA = __builtin_amdgcn_permlane32_swap(w00, w10, false, false);               \
        uint2v rB = __builtin_amdgcn_permlane32_swap(w01, w11, false, false);               \
        uint4v pau = {rA.x, rA.y, rB.x, rB.y};                                              \
        short8 pa = *reinterpret_cast<short8*>(&pau);                                       \
        acc[0] = __builtin_amdgcn_mfma_f32_16x16x32_bf16(pa, v0, acc[0], 0, 0, 0);          \
        acc[1] = __builtin_amdgcn_mfma_f32_16x16x32_bf16(pa, v1, acc[1], 0, 0, 0);          \
        acc[2] = __builtin_amdgcn_mfma_f32_16x16x32_bf16(pa, v2, acc[2], 0, 0, 0);          \
        acc[3] = __builtin_amdgcn_mfma_f32_16x16x32_bf16(pa, v3, acc[3], 0, 0, 0);          \
        acc[4] = __builtin_amdgcn_mfma_f32_16x16x32_bf16(pa, v4, acc[4], 0, 0, 0);          \
        acc[5] = __builtin_amdgcn_mfma_f32_16x16x32_bf16(pa, v5, acc[5], 0, 0, 0);          \
        acc[6] = __builtin_amdgcn_mfma_f32_16x16x32_bf16(pa, v6, acc[6], 0, 0, 0);          \
    } while (0)

__launch_bounds__(512)
__global__ void fused_kernel(const float* __restrict__ gumbel,
                             const ushort* __restrict__ khiA, const ushort* __restrict__ kloA,
                             const ushort* __restrict__ qBhi, const ushort* __restrict__ qBlo,
                             const float* __restrict__ Mg,
                             const ushort* __restrict__ genZB,
                             float* __restrict__ part, float* __restrict__ Lpart) {
    __shared__ __align__(16) ushort vlds[7 * 8192];   // 112 KB: V slice, db-major
    const int t = threadIdx.x, lane = t & 63, w = t >> 6;
    const int b = blockIdx.x;
    const int q = b & 15;          // slice; slices s and s+8 share an XCD (K slice L2-hot)
    const int ib = b >> 4;         // 16 blocks per slice
    // ---- stage V slice (7 contiguous 16KB pieces, linear copy)
    {
        f32x4* vdst = reinterpret_cast<f32x4*>(vlds);
        const f32x4* vsrc = reinterpret_cast<const f32x4*>(genZB);
        for (int i = t; i < 7168; i += 512) {
            int db = i >> 10, rem = i & 1023;
            vdst[i] = vsrc[db * 16384 + q * 1024 + rem];
        }
    }
    __syncthreads();   // the only barrier

    const int gx = lane & 15, bq = lane >> 4;
    const int cmap4 = (((bq & 1) << 1) | (bq >> 1)) << 2;   // {0,8,4,12}
    const ushort* kbase  = khiA + q * 16384 + lane * 8;
    const ushort* klbase = kloA + q * 16384 + lane * 8;
    const f32x4 z4 = {0.f, 0.f, 0.f, 0.f};

    for (int u = ib * 8 + w; u < NGB; u += 128) {
        const float negM = -Mg[u * 16 + gx];
        short8 qh = ld8(qBhi + (size_t)u * 512 + lane * 8);
        short8 ql = ld8(qBlo + (size_t)u * 512 + lane * 8);
        const float* gp = gumbel + (size_t)(u * 16 + gx) * NCELL + q * 512 + cmap4;
        const ushort* kp  = kbase;
        const ushort* klp = klbase;
        const ushort* vp  = vlds + lane * 8;
        f32x4 acc[7];
#pragma unroll
        for (int i = 0; i < 7; ++i) acc[i] = z4;
        float L = 0.f;
        // prologue: A <- step 0
        short8 khA0 = ld8(kp),   khA1 = ld8(kp + 512);
        short8 klA0 = ld8(klp),  klA1 = ld8(klp + 512);
        f32x4  uA0  = ld4(gp),   uA1  = ld4(gp + 16);
        kp += 1024; klp += 1024; gp += 32;
        for (int it = 0; it < 7; ++it) {
            short8 khB0 = ld8(kp),   khB1 = ld8(kp + 512);
            short8 klB0 = ld8(klp),  klB1 = ld8(klp + 512);
            f32x4  uB0  = ld4(gp),   uB1  = ld4(gp + 16);
            STEP_COMPUTE(khA0, khA1, klA0, klA1, uA0, uA1);
            khA0 = ld8(kp + 1024);  khA1 = ld8(kp + 1536);
            klA0 = ld8(klp + 1024); klA1 = ld8(klp + 1536);
            uA0  = ld4(gp + 32);    uA1  = ld4(gp + 48);
            kp += 2048; klp += 2048; gp += 64;
            STEP_COMPUTE(khB0, khB1, klB0, klB1, uB0, uB1);
        }
        {   // peeled steps 14,15
            short8 khB0 = ld8(kp),   khB1 = ld8(kp + 512);
            short8 klB0 = ld8(klp),  klB1 = ld8(klp + 512);
            f32x4  uB0  = ld4(gp),   uB1  = ld4(gp + 16);
            STEP_COMPUTE(khA0, khA1, klA0, klA1, uA0, uA1);
            STEP_COMPUTE(khB0, khB1, klB0, klB1, uB0, uB1);
        }
        // L: lanes sharing gx hold disjoint-cell partials of the same gene
        L += __shfl_xor(L, 16, 64);
        L += __shfl_xor(L, 32, 64);
        const int wv = q * NGB + u;
        if (lane < 16)
            Lpart[(size_t)wv * 16 + lane] = L;
        float* pp = part + (size_t)wv * 7 * 256;
#pragma unroll
        for (int tile = 0; tile < 7; ++tile)
            *reinterpret_cast<f32x4*>(pp + tile * 256 + lane * 4) = acc[tile];
    }
}

// ---------------- Kernel 5: combine 16 slice-partials + normalize
__global__ void combine_kernel(const float* __restrict__ part, const float* __restrict__ Lpart,
                               float* __restrict__ out) {
    const int gb = blockIdx.x;   // 625
    const int t = threadIdx.x;   // 512
    __shared__ float Linv[16];
    if (t < 16) {
        float s = 0.f;
        for (int qq = 0; qq < QSL; ++qq) s += Lpart[(size_t)(qq * NGB + gb) * 16 + t];
        Linv[t] = 1.0f / s;
    }
    __syncthreads();
    if (t < 448) {
        const int tile = t >> 6, lane = t & 63;
        const int d = tile * 16 + (lane & 15);
        f32x4 ssum = {0.f, 0.f, 0.f, 0.f};
        for (int qq = 0; qq < QSL; ++qq)
            ssum += *reinterpret_cast<const f32x4*>(
                part + ((size_t)(qq * NGB + gb) * 7 + tile) * 256 + lane * 4);
        if (d < GD) {
            const int gl0 = 4 * (lane >> 4);   // C/D: col=lane&15 (d), row=4*(lane>>4)+r (gene)
            f32x4 li = {Linv[gl0], Linv[gl0 + 1], Linv[gl0 + 2], Linv[gl0 + 3]};
            f32x4 o = ssum * li;
            *reinterpret_cast<f32x4*>(out + (size_t)d * NGENE + gb * 16 + gl0) = o;
        }
    }
}

extern "C" void kernel_launch(void* const* d_in, const int* in_sizes, int n_in,
                              void* d_out, int out_size, void* d_ws, size_t ws_size,
                              hipStream_t stream) {
    const float* rawZ  = (const float*)d_in[0];
    const float* genZ  = (const float*)d_in[1];
    const float* Grep  = (const float*)d_in[2];
    const float* gumb  = (const float*)d_in[3];
    const float* Wz1   = (const float*)d_in[4];
    const float* bz1   = (const float*)d_in[5];
    const float* Wz2   = (const float*)d_in[6];
    const float* bz2   = (const float*)d_in[7];
    const float* Wg1   = (const float*)d_in[8];
    const float* bg1   = (const float*)d_in[9];
    const float* Wg2   = (const float*)d_in[10];
    const float* bg2   = (const float*)d_in[11];
    float* out = (float*)d_out;

    char* ws = (char*)d_ws;
    ushort*   khiA  = (ushort*)ws;                           // 512K
    ushort*   kloA  = (ushort*)(ws + 524288);                // 512K
    ushort*   qBhi  = (ushort*)(ws + 1048576);               // 640K (10016 genes)
    ushort*   qBlo  = (ushort*)(ws + 1703936);               // 640K
    ushort*   genZB = (ushort*)(ws + 2359296);               // 1.75M (7 db, db-major)
    float*    MgA   = (float*)(ws + 4456448);                // 40K
    unsigned* kmax  = (unsigned*)(ws + 4497408);             // 256B
    const size_t base_off = 4497664;

    float* partA  = (float*)(ws + base_off);                 // 16*625*7*256*4 = 71.7 MB
    float* LpartA = partA + (size_t)QSL * NGB * 7 * 256;     // 640 KB

    hipMemsetAsync(kmax, 0, 4, stream);
    hipLaunchKernelGGL(key_kernel,   dim3(NCELL / 8), dim3(256), 0, stream,
                       rawZ, Wz1, bz1, Wz2, bz2, khiA, kloA, kmax);
    hipLaunchKernelGGL(query_kernel, dim3(NGPAD / 8), dim3(256), 0, stream,
                       Grep, Wg1, bg1, Wg2, bg2, kmax, qBhi, qBlo, MgA);
    hipLaunchKernelGGL(vprep_kernel, dim3(917504 / 256), dim3(256), 0, stream,
                       genZ, genZB);
    hipLaunchKernelGGL(fused_kernel, dim3(256), dim3(512), 0, stream,
                       gumb, khiA, kloA, qBhi, qBlo, MgA, genZB, partA, LpartA);
    hipLaunchKernelGGL(combine_kernel, dim3(NGB), dim3(512), 0, stream,
                       partA, LpartA, out);
}